// Round 10
// baseline (340.139 us; speedup 1.0000x reference)
//
#include <hip/hip_runtime.h>
#include <hip/hip_bf16.h>
#include <cstdint>
#include <cstddef>

typedef __bf16 bf16_t;
typedef __bf16 bf16x8 __attribute__((ext_vector_type(8)));
typedef __bf16 bf16x4v __attribute__((ext_vector_type(4)));
typedef __bf16 bf16x2v __attribute__((ext_vector_type(2)));
typedef float f32x4 __attribute__((ext_vector_type(4)));
typedef float f32x16 __attribute__((ext_vector_type(16)));
typedef uint32_t u32x4 __attribute__((ext_vector_type(4)));
typedef uint32_t u32x2 __attribute__((ext_vector_type(2)));

#define DEVI static __device__ __forceinline__

// async global->LDS, 16B per lane. LDS dest must be wave-uniform base + lane*16.
DEVI void gl_lds16(const void* g, void* l) {
    __builtin_amdgcn_global_load_lds((const __attribute__((address_space(1))) void*)g,
                                     (__attribute__((address_space(3))) void*)l, 16, 0, 0);
}

DEVI float fexp2(float x) {
#if __has_builtin(__builtin_amdgcn_exp2f)
    return __builtin_amdgcn_exp2f(x);
#else
    return __expf(x * 0.6931471805599453f);
#endif
}

DEVI uint32_t pkbf16(float a, float b) {
    bf16x2v t;
    t[0] = (bf16_t)a;
    t[1] = (bf16_t)b;
    return __builtin_bit_cast(uint32_t, t);
}

// ---------------- merged prep: cast QKV + weight-transpose + RoPE tables ----------------
// One launch instead of three (castk/wtrans/rope_tab) to cut inter-dispatch gaps.
// Flat grid, block-uniform branch by blockIdx range:
//   [0, 24576)        cast fp32->bf16: 3 tensors x 8192 blocks (1024 elem/block)
//   [24576, 28672)    wtrans: 4 weights x 1024 tiles of 32x32
//   [28672, 28928)    rope tables: 65536 elements
__global__ __launch_bounds__(256) void prep(const float* __restrict__ q, const float* __restrict__ k,
                                            const float* __restrict__ v, bf16_t* __restrict__ oq,
                                            bf16_t* __restrict__ ok, bf16_t* __restrict__ ov,
                                            const float* __restrict__ W0, const float* __restrict__ W1,
                                            const float* __restrict__ W2, const float* __restrict__ W3,
                                            bf16_t* __restrict__ O0, bf16_t* __restrict__ O1,
                                            bf16_t* __restrict__ O2, bf16_t* __restrict__ O3,
                                            float* __restrict__ ctab, float* __restrict__ stab) {
    const int bid = blockIdx.x;
    if (bid < 24576) {
        int t = bid >> 13;                      // /8192
        int pos = bid & 8191;
        const float* in = t == 0 ? q : t == 1 ? k : v;
        bf16_t* out = t == 0 ? oq : t == 1 ? ok : ov;
        size_t i = ((size_t)pos * 256 + threadIdx.x) * 4;
        float4 vv = *(const float4*)(in + i);
        bf16x4v o;
        o[0] = (bf16_t)vv.x; o[1] = (bf16_t)vv.y; o[2] = (bf16_t)vv.z; o[3] = (bf16_t)vv.w;
        *(bf16x4v*)(out + i) = o;
    } else if (bid < 28672) {
        int widx = bid - 24576;
        int z = widx >> 10;
        int tile = widx & 1023;
        const float* W; bf16_t* O;
        switch (z) {
            case 0: W = W0; O = O0; break;
            case 1: W = W1; O = O1; break;
            case 2: W = W2; O = O2; break;
            default: W = W3; O = O3; break;
        }
        __shared__ float tbuf[32][33];
        int tx = threadIdx.x & 31, ty = threadIdx.x >> 5;   // 32x8
        int bx = (tile & 31) * 32, by = (tile >> 5) * 32;   // bx: n, by: k
#pragma unroll
        for (int yy = 0; yy < 4; ++yy)
            tbuf[ty + yy * 8][tx] = W[(size_t)(by + ty + yy * 8) * 1024 + bx + tx];
        __syncthreads();
#pragma unroll
        for (int yy = 0; yy < 4; ++yy)
            O[(size_t)(bx + ty + yy * 8) * 1024 + by + tx] = (bf16_t)tbuf[tx][ty + yy * 8];
    } else {
        int idx = (bid - 28672) * 256 + threadIdx.x;        // 65536 = 2048*32
        int s = idx >> 5, i = idx & 31;
        float inv = 1.0f / powf(10000.0f, (float)i * (1.0f / 32.0f));
        float f = (float)s * inv;
        ctab[idx] = cosf(f);
        stab[idx] = sinf(f);
    }
}

// ---------------- fused QKV projection GEMM (grid.z selects Q/K/V) ----------------
// Grid (64,8,3): blockIdx.x = M-row tile; linear%8 = x%8, so the 8 N-tiles of one M-row
// share an XCD's L2 (A row-tile fetched once per XCD).
// BK=64: 16 K-iterations — halves the per-iter vmcnt(0)+barrier drain (r7: WIN).
// T2 swizzle for 128B rows: 16B-chunk index XOR'd with row&7, inverse-swizzled GLOBAL
// source + linear gl_lds16 dest + swizzled read. Conflict-free frag reads.
__global__ __launch_bounds__(256) void gemm_qkv(const bf16_t* __restrict__ Xq, const bf16_t* __restrict__ Xk,
                                                const bf16_t* __restrict__ Xv, const bf16_t* __restrict__ Wqt,
                                                const bf16_t* __restrict__ Wkt, const bf16_t* __restrict__ Wvt,
                                                const float* __restrict__ bqp, const float* __restrict__ bkp,
                                                const float* __restrict__ bvp, bf16_t* __restrict__ Qo,
                                                bf16_t* __restrict__ Ko, bf16_t* __restrict__ Vo,
                                                const float* __restrict__ ctab, const float* __restrict__ stab) {
    constexpr int K = 1024;
    const int z = blockIdx.z;
    const bf16_t* A  = z == 0 ? Xq : z == 1 ? Xk : Xv;
    const bf16_t* Bt = z == 0 ? Wqt : z == 1 ? Wkt : Wvt;
    const float* bias = z == 0 ? bqp : z == 1 ? bkp : bvp;
    bf16_t* O = z == 0 ? Qo : z == 1 ? Ko : Vo;
    const float scale = z == 0 ? 0.18033688011112042f : 1.0f;   // log2(e)/8 folded into Q

    __shared__ alignas(16) bf16_t As[128 * 64];   // 16KB
    __shared__ alignas(16) bf16_t Bs[128 * 64];   // 16KB
    const int tid = threadIdx.x;
    const int w = tid >> 6, lane = tid & 63, c = lane & 15, qd = lane >> 4;
    const int wm = w >> 1, wn = w & 1;
    const int c7 = c & 7;                         // row&7 of every frag-read row
    const int m0 = blockIdx.x * 128, n0 = blockIdx.y * 128;
    f32x4 acc[4][4] = {};
    for (int kt = 0; kt < K / 64; ++kt) {
#pragma unroll
        for (int l = 0; l < 4; ++l) {
            int slot = l * 256 + tid;             // 16B slots: row = slot>>3, chunk = slot&7
            int row = slot >> 3, ch = slot & 7;
            int sch = ch ^ (row & 7);             // inverse-swizzled source, linear dest
            gl_lds16(A + (size_t)(m0 + row) * K + kt * 64 + sch * 8, (char*)As + (size_t)slot * 16);
            gl_lds16(Bt + (size_t)(n0 + row) * K + kt * 64 + sch * 8, (char*)Bs + (size_t)slot * 16);
        }
        __syncthreads();
#pragma unroll
        for (int kk = 0; kk < 2; ++kk) {
            const int cs8 = (kk * 4 + qd) ^ c7;   // swizzled chunk for k-slice kk
            bf16x8 af[4], bfr[4];
#pragma unroll
            for (int i = 0; i < 4; ++i)
                af[i] = *(const bf16x8*)&As[(wm * 64 + i * 16 + c) * 64 + cs8 * 8];
#pragma unroll
            for (int j = 0; j < 4; ++j)
                bfr[j] = *(const bf16x8*)&Bs[(wn * 64 + j * 16 + c) * 64 + cs8 * 8];
#pragma unroll
            for (int i = 0; i < 4; ++i)
#pragma unroll
                for (int j = 0; j < 4; ++j)
                    acc[i][j] = __builtin_amdgcn_mfma_f32_16x16x32_bf16(af[i], bfr[j], acc[i][j], 0, 0, 0);
        }
        __syncthreads();
    }
    const int mb = m0 + wm * 64;
    const int nb = n0 + wn * 64;   // head-aligned (64): nb>>6 = head
    const int h = nb >> 6;
    if (z == 2) {
        // V: store transposed Vt[b,h,d,s], packing 4 consecutive s per store
#pragma unroll
        for (int i = 0; i < 4; ++i) {
            int m = mb + i * 16 + qd * 4;     // 4 consecutive s at r=0..3, same b
            int b = m >> 11, s = m & 2047;
#pragma unroll
            for (int j = 0; j < 4; ++j) {
                int d = j * 16 + c;
                float bv = bias[nb + d];
                bf16x4v v4;
#pragma unroll
                for (int r = 0; r < 4; ++r) v4[r] = (bf16_t)(acc[i][j][r] + bv);
                *(bf16x4v*)(O + ((size_t)(b * 16 + h) * 64 + d) * 2048 + s) = v4;
            }
        }
    } else {
#pragma unroll
        for (int i = 0; i < 4; ++i)
#pragma unroll
            for (int jh = 0; jh < 2; ++jh) {
                int d1 = jh * 16 + c;                 // [0,32)
                float b1 = bias[nb + d1];
                float b2 = bias[nb + d1 + 32];
#pragma unroll
                for (int r = 0; r < 4; ++r) {
                    int m = mb + i * 16 + qd * 4 + r;
                    int b = m >> 11, s = m & 2047;
                    float v1 = acc[i][jh][r] + b1;
                    float v2 = acc[i][jh + 2][r] + b2;
                    float ct = ctab[s * 32 + d1];
                    float st = stab[s * 32 + d1];
                    size_t base = ((size_t)(b * 16 + h) * 2048 + s) * 64;
                    O[base + d1]      = (bf16_t)((v1 * ct - v2 * st) * scale);
                    O[base + d1 + 32] = (bf16_t)((v2 * ct + v1 * st) * scale);
                }
            }
    }
}

// ---------------- out-proj GEMM: fp32 store [m,n] + bias. Grid (64,8), x = M-tile ----------------
// Same BK=64 + row&7 chunk swizzle as gemm_qkv.
__global__ __launch_bounds__(256) void gemm_out(const bf16_t* __restrict__ A, const bf16_t* __restrict__ Bt,
                                                const float* __restrict__ bias, float* __restrict__ O) {
    constexpr int K = 1024, N = 1024;
    __shared__ alignas(16) bf16_t As[128 * 64];
    __shared__ alignas(16) bf16_t Bs[128 * 64];
    const int tid = threadIdx.x;
    const int w = tid >> 6, lane = tid & 63, c = lane & 15, qd = lane >> 4;
    const int wm = w >> 1, wn = w & 1;
    const int c7 = c & 7;
    const int m0 = blockIdx.x * 128, n0 = blockIdx.y * 128;
    f32x4 acc[4][4] = {};
    for (int kt = 0; kt < K / 64; ++kt) {
#pragma unroll
        for (int l = 0; l < 4; ++l) {
            int slot = l * 256 + tid;
            int row = slot >> 3, ch = slot & 7;
            int sch = ch ^ (row & 7);
            gl_lds16(A + (size_t)(m0 + row) * K + kt * 64 + sch * 8, (char*)As + (size_t)slot * 16);
            gl_lds16(Bt + (size_t)(n0 + row) * K + kt * 64 + sch * 8, (char*)Bs + (size_t)slot * 16);
        }
        __syncthreads();
#pragma unroll
        for (int kk = 0; kk < 2; ++kk) {
            const int cs8 = (kk * 4 + qd) ^ c7;
            bf16x8 af[4], bfr[4];
#pragma unroll
            for (int i = 0; i < 4; ++i)
                af[i] = *(const bf16x8*)&As[(wm * 64 + i * 16 + c) * 64 + cs8 * 8];
#pragma unroll
            for (int j = 0; j < 4; ++j)
                bfr[j] = *(const bf16x8*)&Bs[(wn * 64 + j * 16 + c) * 64 + cs8 * 8];
#pragma unroll
            for (int i = 0; i < 4; ++i)
#pragma unroll
                for (int j = 0; j < 4; ++j)
                    acc[i][j] = __builtin_amdgcn_mfma_f32_16x16x32_bf16(af[i], bfr[j], acc[i][j], 0, 0, 0);
        }
        __syncthreads();
    }
    const int mb = m0 + wm * 64, nb = n0 + wn * 64;
#pragma unroll
    for (int i = 0; i < 4; ++i)
#pragma unroll
        for (int j = 0; j < 4; ++j) {
            int n = nb + j * 16 + c;
            float bv = bias[n];
#pragma unroll
            for (int r = 0; r < 4; ++r) {
                int m = mb + i * 16 + qd * 4 + r;
                O[(size_t)m * N + n] = acc[i][j][r] + bv;
            }
        }
}

// ---------------- flash attention v10: v7+prio + start-phase stagger ----------------
// r9 analysis: per-CU window = 6220 cyc, MFMA work 2704 (43%), VALU ~43% — the 4
// independent blocks/CU launch simultaneously with identical instruction streams and
// stay phase-aligned by symmetry, so the MFMA and VALU pipes ALTERNATE instead of
// overlapping. v10 breaks the symmetry with a ONE-TIME s_sleep stagger at loop entry
// (phase = hash(block)&3, ~1.7k cyc/step ≈ 1/4 window): K-tile order and same-bh L2
// sharing untouched (r6's rotation failure mode avoided), cost <=2.4us once, and the
// offset persists (nothing re-synchronizes blocks).
// Structure otherwise identical to r9: swapped QK, permlane32 St->PV transform,
// ones-B-frag row sums, setprio on MFMA clusters, chunk-XOR swizzled LDS.
__global__ __launch_bounds__(256, 4) void attn(const bf16_t* __restrict__ Q, const bf16_t* __restrict__ K,
                                               const bf16_t* __restrict__ Vt, bf16_t* __restrict__ ctx) {
    constexpr int S = 2048;
    __shared__ alignas(16) char smem[32768];   // Q stage 16KB -> [buf][K 8KB | V 8KB] x2
    const int tid = threadIdx.x, w = tid >> 6, lane = tid & 63;
    const int lo5 = lane & 31, hi = lane >> 5;
    const int rm = (lo5 >> 1) & 7;              // read-side swizzle mask (row mod 16)/2
    const int bh = blockIdx.x, q0 = blockIdx.y * 128;
    const bf16_t* Qb = Q + (size_t)bh * S * 64 + (size_t)q0 * 64;
    const bf16_t* Kb = K + (size_t)bh * S * 64;
    const bf16_t* Vb = Vt + (size_t)bh * 64 * S;
    // ---- stage Q (128x64 = 16KB), read B-frags, recycle region ----
#pragma unroll
    for (int l = 0; l < 4; ++l) {
        int slot = l * 256 + tid;               // 16B slots
        int row = slot >> 3, ch = slot & 7;
        int sch = ch ^ ((row >> 1) & 7);
        gl_lds16(Qb + (size_t)row * 64 + sch * 8, smem + (size_t)slot * 16);
    }
    __syncthreads();
    bf16x8 qf[4];                               // [kc]: B[n=q=w*32+lo5][k=d=kc*16+hi*8+j]
    {
        const bf16_t* Qs = (const bf16_t*)smem;
#pragma unroll
        for (int kc = 0; kc < 4; ++kc)
            qf[kc] = *(const bf16x8*)&Qs[(size_t)(w * 32 + lo5) * 64 + ((kc * 2 + hi) ^ rm) * 8];
    }
    __syncthreads();                            // all waves done reading Q
    // ---- start-phase stagger: de-phase co-resident blocks (block-uniform, no
    // barrier divergence; one-time cost <= ~2.4us for phase 3) ----
    {
        unsigned lin = blockIdx.y * 64u + blockIdx.x;
        int ph = (int)((lin ^ (lin >> 2) ^ (lin >> 4)) & 3u);
        for (int i = 0; i < ph; ++i) {
            __builtin_amdgcn_s_sleep(15);       // ~960 cyc
            __builtin_amdgcn_s_sleep(12);       // ~768 cyc
        }
    }
    auto stageKV = [&](int kt, int buf) {
        const int s0 = kt * 64;
        char* kbase = smem + buf * 16384;
        char* vbase = kbase + 8192;
#pragma unroll
        for (int l = 0; l < 2; ++l) {
            int slot = l * 256 + tid;
            int row = slot >> 3, ch = slot & 7;
            int sch = ch ^ ((row >> 1) & 7);
            gl_lds16(Kb + (size_t)(s0 + row) * 64 + sch * 8, kbase + (size_t)slot * 16);
            gl_lds16(Vb + (size_t)row * S + s0 + sch * 8, vbase + (size_t)slot * 16);
        }
    };
    stageKV(0, 0);
    f32x16 acc_o[2] = {};                       // [db]
    f32x16 acc_l = {};                          // row-sums (all cols equal)
    const f32x16 Z16 = {};
    bf16x8 ones;
    {
        u32x4 ov = {0x3F803F80u, 0x3F803F80u, 0x3F803F80u, 0x3F803F80u};
        ones = __builtin_bit_cast(bf16x8, ov);
    }
    __syncthreads();                            // tile 0 staged
    for (int kt = 0; kt < S / 64; ++kt) {
        const int cur = kt & 1;
        if (kt + 1 < S / 64) stageKV(kt + 1, cur ^ 1);
        const bf16_t* KsC = (const bf16_t*)(smem + cur * 16384);
        const bf16_t* VsC = (const bf16_t*)(smem + cur * 16384 + 8192);
        // St[s][q]: A=K[m=s=sb*32+lo5][k=d], B=Q
        f32x16 st[2];                           // [sb]
        __builtin_amdgcn_s_setprio(1);
#pragma unroll
        for (int kc = 0; kc < 4; ++kc) {
            bf16x8 kf[2];
#pragma unroll
            for (int sb = 0; sb < 2; ++sb)
                kf[sb] = *(const bf16x8*)&KsC[(size_t)(sb * 32 + lo5) * 64 + ((kc * 2 + hi) ^ rm) * 8];
#pragma unroll
            for (int sb = 0; sb < 2; ++sb)
                st[sb] = __builtin_amdgcn_mfma_f32_32x32x16_bf16(kf[sb], qf[kc],
                                                                 kc == 0 ? Z16 : st[sb], 0, 0, 0);
        }
        __builtin_amdgcn_s_setprio(0);
        // p = 2^st, pack s-pairs: pku[sb][u] covers s = sb*32 + 8*(u>>1) + 4*hi + 2*(u&1) + {0,1}
        uint32_t pku[2][8];
#pragma unroll
        for (int sb = 0; sb < 2; ++sb)
#pragma unroll
            for (int u = 0; u < 8; ++u)
                pku[sb][u] = pkbf16(fexp2(st[sb][2 * u]), fexp2(st[sb][2 * u + 1]));
        // PV: A = P[m=q][k=s chunk skc], B = V[n=d][k=s]; plus l via ones B-frag
        __builtin_amdgcn_s_setprio(1);
#pragma unroll
        for (int skc = 0; skc < 4; ++skc) {
            bf16x8 vf[2];
#pragma unroll
            for (int db = 0; db < 2; ++db)
                vf[db] = *(const bf16x8*)&VsC[(size_t)(db * 32 + lo5) * 64 + ((skc * 2 + hi) ^ rm) * 8];
            const int sb = skc >> 1, b = (skc & 1) * 4;
            uint32_t p0 = pku[sb][b + 0], p1 = pku[sb][b + 1];
            uint32_t p2 = pku[sb][b + 2], p3 = pku[sb][b + 3];
#if __has_builtin(__builtin_amdgcn_permlane32_swap)
            u32x2 r02 = __builtin_amdgcn_permlane32_swap(p0, p2, false, false);
            u32x2 r13 = __builtin_amdgcn_permlane32_swap(p1, p3, false, false);
            u32x4 av = {r02[0], r13[0], r02[1], r13[1]};
#else
            uint32_t send0 = hi ? p0 : p2;
            uint32_t send1 = hi ? p1 : p3;
            uint32_t recv0 = __shfl_xor(send0, 32);
            uint32_t recv1 = __shfl_xor(send1, 32);
            u32x4 av = {hi ? recv0 : p0, hi ? recv1 : p1,
                        hi ? p2 : recv0, hi ? p3 : recv1};
#endif
            bf16x8 af = __builtin_bit_cast(bf16x8, av);
            acc_l = __builtin_amdgcn_mfma_f32_32x32x16_bf16(af, ones, acc_l, 0, 0, 0);
#pragma unroll
            for (int db = 0; db < 2; ++db)
                acc_o[db] = __builtin_amdgcn_mfma_f32_32x32x16_bf16(af, vf[db], acc_o[db], 0, 0, 0);
        }
        __builtin_amdgcn_s_setprio(0);
        __syncthreads();
    }
    // epilogue: o = acc_o / acc_l (rows aligned); C row = (reg&3)+8*(reg>>2)+4*hi, col = lo5
    const int b = bh >> 4, h = bh & 15;
    float linv[16];
#pragma unroll
    for (int r = 0; r < 16; ++r) linv[r] = 1.0f / acc_l[r];
#pragma unroll
    for (int db = 0; db < 2; ++db)
#pragma unroll
        for (int r = 0; r < 16; ++r) {
            int qrow = q0 + w * 32 + (r & 3) + 8 * (r >> 2) + 4 * hi;
            int d = db * 32 + lo5;
            float o = acc_o[db][r] * linv[r];
            ctx[((size_t)(b * 2048 + qrow)) * 1024 + (size_t)h * 64 + d] = (bf16_t)o;
        }
}

extern "C" void kernel_launch(void* const* d_in, const int* in_sizes, int n_in,
                              void* d_out, int out_size, void* d_ws, size_t ws_size,
                              hipStream_t stream) {
    (void)in_sizes; (void)n_in; (void)out_size; (void)ws_size;
    const float* query = (const float*)d_in[0];
    const float* key   = (const float*)d_in[1];
    const float* value = (const float*)d_in[2];
    const float* Wq = (const float*)d_in[3];
    const float* bq = (const float*)d_in[4];
    const float* Wk = (const float*)d_in[5];
    const float* bk = (const float*)d_in[6];
    const float* Wv = (const float*)d_in[7];
    const float* bv = (const float*)d_in[8];
    const float* Wo = (const float*)d_in[9];
    const float* bo = (const float*)d_in[10];

    const size_t SZ = (size_t)8192 * 1024;
    bf16_t* Xq = (bf16_t*)d_ws;
    bf16_t* Xk = Xq + SZ;
    bf16_t* Xv = Xk + SZ;
    bf16_t* Qb = Xv + SZ;
    bf16_t* Kb = Qb + SZ;
    bf16_t* Vtb = Kb + SZ;
    bf16_t* Wqt = Vtb + SZ;
    bf16_t* Wkt = Wqt + 1024 * 1024;
    bf16_t* Wvt = Wkt + 1024 * 1024;
    bf16_t* Wot = Wvt + 1024 * 1024;
    float* ctab = (float*)(Wot + 1024 * 1024);
    float* stab = ctab + 2048 * 32;
    bf16_t* CT = Xq;                // alias: Xq dead after projection GEMM

    prep<<<dim3(28928), 256, 0, stream>>>(query, key, value, Xq, Xk, Xv,
                                          Wq, Wk, Wv, Wo, Wqt, Wkt, Wvt, Wot, ctab, stab);
    gemm_qkv<<<dim3(64, 8, 3), 256, 0, stream>>>(Xq, Xk, Xv, Wqt, Wkt, Wvt, bq, bk, bv,
                                                 Qb, Kb, Vtb, ctab, stab);
    attn<<<dim3(64, 16), 256, 0, stream>>>(Qb, Kb, Vtb, CT);
    gemm_out<<<dim3(64, 8), 256, 0, stream>>>(CT, Wot, bo, (float*)d_out);
}